// Round 2
// 301.113 us; speedup vs baseline: 1.0479x; 1.0479x over previous
//
#include <hip/hip_runtime.h>

#define N_  8
#define C_  3
#define HD_ 1024
#define WD_ 1280
#define HS_ 800
#define WS_ 1280

// native vector type accepted by __builtin_nontemporal_load
typedef float fx4 __attribute__((ext_vector_type(4)));

// ---------- helpers ----------
__device__ __forceinline__ unsigned short f2bf(float f) {
    unsigned int u = __float_as_uint(f);
    unsigned int r = (u + 0x7FFFu + ((u >> 16) & 1u)) >> 16;  // RNE
    return (unsigned short)r;
}
__device__ __forceinline__ float bf2f(unsigned int h) {
    return __uint_as_float(h << 16);
}

// Bijective chunked XCD swizzle (m204): XCD k gets a contiguous chunk of the
// grid. With nwg = 40960 = 8*5120 this maps image n -> XCD n exactly, so each
// XCD's in-flight gather band (~1 MB) fits its private 4 MB L2.
__device__ __forceinline__ int xcd_chunk_swizzle(int bid, int nwg) {
    const int NX = 8;
    int q = nwg / NX, r = nwg % NX;
    int xcd = bid % NX;
    int lid = bid / NX;
    return (xcd < r) ? (xcd * (q + 1) + lid)
                     : (r * (q + 1) + (xcd - r) * q + lid);
}

// ---------- pass 1: interleave src [N,3,HS,WS] fp32 -> [N,HS,WS] {bf16 c0,c1,c2,pad} (8B/px) ----------
__global__ __launch_bounds__(256) void interleave_kernel(
    const float* __restrict__ src, uint4* __restrict__ ws)
{
    const size_t HWs = (size_t)HS_ * WS_;
    size_t g = (size_t)blockIdx.x * blockDim.x + threadIdx.x;  // group of 4 pixels
    size_t base = g * 4;
    if (base >= (size_t)N_ * HWs) return;
    int n = (int)(base / HWs);
    size_t p = base - (size_t)n * HWs;
    const float* s = src + (size_t)n * C_ * HWs + p;
    // src fp32 is read exactly once -> nontemporal, don't evict useful lines.
    fx4 c0 = __builtin_nontemporal_load((const fx4*)(s));
    fx4 c1 = __builtin_nontemporal_load((const fx4*)(s + HWs));
    fx4 c2 = __builtin_nontemporal_load((const fx4*)(s + 2 * HWs));

    uint4 A, B;
    A.x = (unsigned)f2bf(c0.x) | ((unsigned)f2bf(c1.x) << 16);
    A.y = (unsigned)f2bf(c2.x);
    A.z = (unsigned)f2bf(c0.y) | ((unsigned)f2bf(c1.y) << 16);
    A.w = (unsigned)f2bf(c2.y);
    B.x = (unsigned)f2bf(c0.z) | ((unsigned)f2bf(c1.z) << 16);
    B.y = (unsigned)f2bf(c2.z);
    B.z = (unsigned)f2bf(c0.w) | ((unsigned)f2bf(c1.w) << 16);
    B.w = (unsigned)f2bf(c2.w);

    size_t o = base / 2;  // uint4 = 2 pixels
    // ws is read back by pass 2 -> KEEP cached (L3 should retain it).
    ws[o]     = A;
    ws[o + 1] = B;
}

// ---------- pass 2: warp + bilinear gather from interleaved bf16 ----------
__global__ __launch_bounds__(256) void warp_main_kernel(
    const float* __restrict__ depth,   // [N,1,HD,WD]
    const uint2* __restrict__ wsrc,    // [N,HS,WS] packed
    const float* __restrict__ abc,     // [3,HD,WD]
    const float* __restrict__ tr,      // [3]
    const float* __restrict__ pin,     // [4]
    float* __restrict__ out)           // [N,C,HD,WD]
{
    const int HW = HD_ * WD_;
    int swz = xcd_chunk_swizzle(blockIdx.x, gridDim.x);
    int idx = swz * blockDim.x + threadIdx.x;
    if (idx >= N_ * HW) return;

    int n  = idx / HW;
    int hw = idx - n * HW;

    // depth read exactly once -> nontemporal.
    float d = __builtin_nontemporal_load(&depth[idx]);
    // abc is shared by all 8 XCDs marching in row-lockstep -> keep cached.
    float a = abc[hw];
    float b = abc[HW + hw];
    float c = abc[2 * HW + hw];

    float tx = tr[0], ty = tr[1], tz = tr[2];
    float fu = pin[0], fv = pin[1], du = pin[2], dv = pin[3];

    float denom = c * d + tz;
    float inv = 1.0f / denom;
    float xx = (a * d + tx) * inv;
    float yy = (b * d + ty) * inv;
    float uu = fu * xx + du;
    float vv = fv * yy + dv;

    float gx = 2.0f * uu / (float)(WS_ - 1) - 1.0f;
    float gy = 2.0f * vv / (float)(HS_ - 1) - 1.0f;
    float x = ((gx + 1.0f) * (float)WS_ - 1.0f) * 0.5f;
    float y = ((gy + 1.0f) * (float)HS_ - 1.0f) * 0.5f;

    x = fminf(fmaxf(x, 0.0f), (float)(WS_ - 1));
    y = fminf(fmaxf(y, 0.0f), (float)(HS_ - 1));

    float x0f = floorf(x);
    float y0f = floorf(y);
    float wx = x - x0f;
    float wy = y - y0f;
    int x0 = (int)x0f;
    int y0 = (int)y0f;
    int x1 = min(x0 + 1, WS_ - 1);
    int y1 = min(y0 + 1, HS_ - 1);

    float w00 = (1.0f - wy) * (1.0f - wx);
    float w01 = (1.0f - wy) * wx;
    float w10 = wy * (1.0f - wx);
    float w11 = wy * wx;

    const size_t HWs = (size_t)HS_ * WS_;
    const uint2* sn = wsrc + (size_t)n * HWs;
    uint2 t00 = sn[(size_t)y0 * WS_ + x0];
    uint2 t01 = sn[(size_t)y0 * WS_ + x1];
    uint2 t10 = sn[(size_t)y1 * WS_ + x0];
    uint2 t11 = sn[(size_t)y1 * WS_ + x1];

    float* on = out + (size_t)n * C_ * HW + hw;

    // channel 0: low half of .x
    float v0 = bf2f(t00.x & 0xFFFFu) * w00 + bf2f(t01.x & 0xFFFFu) * w01
             + bf2f(t10.x & 0xFFFFu) * w10 + bf2f(t11.x & 0xFFFFu) * w11;
    // channel 1: high half of .x
    float v1 = bf2f(t00.x >> 16) * w00 + bf2f(t01.x >> 16) * w01
             + bf2f(t10.x >> 16) * w10 + bf2f(t11.x >> 16) * w11;
    // channel 2: low half of .y
    float v2 = bf2f(t00.y & 0xFFFFu) * w00 + bf2f(t01.y & 0xFFFFu) * w01
             + bf2f(t10.y & 0xFFFFu) * w10 + bf2f(t11.y & 0xFFFFu) * w11;

    // out is written once, never read -> nontemporal, don't churn L3
    // (keeps packed src resident between pass 1 and pass 2).
    __builtin_nontemporal_store(v0, on);
    __builtin_nontemporal_store(v1, on + (size_t)HW);
    __builtin_nontemporal_store(v2, on + (size_t)2 * HW);
}

// ---------- fallback: round-1 planar kernel (used only if ws too small) ----------
__global__ __launch_bounds__(256) void warp_planar_kernel(
    const float* __restrict__ depth, const float* __restrict__ src,
    const float* __restrict__ abc, const float* __restrict__ tr,
    const float* __restrict__ pin, float* __restrict__ out)
{
    const int HW = HD_ * WD_;
    int idx = blockIdx.x * blockDim.x + threadIdx.x;
    if (idx >= N_ * HW) return;
    int n  = idx / HW;
    int hw = idx - n * HW;
    float d = depth[idx];
    float a = abc[hw];
    float b = abc[HW + hw];
    float c = abc[2 * HW + hw];
    float denom = c * d + tr[2];
    float inv = 1.0f / denom;
    float uu = pin[0] * ((a * d + tr[0]) * inv) + pin[2];
    float vv = pin[1] * ((b * d + tr[1]) * inv) + pin[3];
    float gx = 2.0f * uu / (float)(WS_ - 1) - 1.0f;
    float gy = 2.0f * vv / (float)(HS_ - 1) - 1.0f;
    float x = ((gx + 1.0f) * (float)WS_ - 1.0f) * 0.5f;
    float y = ((gy + 1.0f) * (float)HS_ - 1.0f) * 0.5f;
    x = fminf(fmaxf(x, 0.0f), (float)(WS_ - 1));
    y = fminf(fmaxf(y, 0.0f), (float)(HS_ - 1));
    float x0f = floorf(x), y0f = floorf(y);
    float wx = x - x0f, wy = y - y0f;
    int x0 = (int)x0f, y0 = (int)y0f;
    int x1 = min(x0 + 1, WS_ - 1);
    int y1 = min(y0 + 1, HS_ - 1);
    float w00 = (1.0f - wy) * (1.0f - wx), w01 = (1.0f - wy) * wx;
    float w10 = wy * (1.0f - wx), w11 = wy * wx;
    const size_t HWs = (size_t)HS_ * WS_;
    const float* sn = src + (size_t)n * C_ * HWs;
    int o00 = y0 * WS_ + x0, o01 = y0 * WS_ + x1;
    int o10 = y1 * WS_ + x0, o11 = y1 * WS_ + x1;
    float* on = out + (size_t)n * C_ * HW + hw;
#pragma unroll
    for (int ch = 0; ch < C_; ++ch) {
        const float* sc = sn + (size_t)ch * HWs;
        on[(size_t)ch * HW] = sc[o00] * w00 + sc[o01] * w01
                            + sc[o10] * w10 + sc[o11] * w11;
    }
}

extern "C" void kernel_launch(void* const* d_in, const int* in_sizes, int n_in,
                              void* d_out, int out_size, void* d_ws, size_t ws_size,
                              hipStream_t stream) {
    const float* depth = (const float*)d_in[0];
    const float* src   = (const float*)d_in[1];
    const float* abc   = (const float*)d_in[2];
    const float* tr    = (const float*)d_in[3];
    const float* pin   = (const float*)d_in[4];
    float* out = (float*)d_out;

    const size_t need = (size_t)N_ * HS_ * WS_ * 8;  // 8B per src pixel
    const int total = N_ * HD_ * WD_;
    const int block = 256;

    if (ws_size >= need) {
        const size_t src_px = (size_t)N_ * HS_ * WS_;
        const int g1 = (int)((src_px / 4 + block - 1) / block);
        interleave_kernel<<<g1, block, 0, stream>>>(src, (uint4*)d_ws);
        const int g2 = (total + block - 1) / block;
        warp_main_kernel<<<g2, block, 0, stream>>>(depth, (const uint2*)d_ws,
                                                   abc, tr, pin, out);
    } else {
        const int g = (total + block - 1) / block;
        warp_planar_kernel<<<g, block, 0, stream>>>(depth, src, abc, tr, pin, out);
    }
}

// Round 5
// 295.772 us; speedup vs baseline: 1.0668x; 1.0181x over previous
//
#include <hip/hip_runtime.h>

#define N_  8
#define C_  3
#define HD_ 1024
#define WD_ 1280
#define HS_ 800
#define WS_ 1280

// native vector types accepted by __builtin_nontemporal_load
typedef float fx4 __attribute__((ext_vector_type(4)));
typedef unsigned int u32x4 __attribute__((ext_vector_type(4)));
// 16B vector that is only 8B-aligned (pixel-pair load at arbitrary x0)
typedef u32x4 u32x4a8 __attribute__((aligned(8)));

// ---------- helpers ----------
__device__ __forceinline__ unsigned short f2bf(float f) {
    unsigned int u = __float_as_uint(f);
    unsigned int r = (u + 0x7FFFu + ((u >> 16) & 1u)) >> 16;  // RNE
    return (unsigned short)r;
}
__device__ __forceinline__ float bf2f(unsigned int h) {
    return __uint_as_float(h << 16);
}

// Bijective chunked XCD swizzle (m204): XCD k gets a contiguous chunk of the
// grid -> image n maps to XCD n (nwg = 40960 = 8*5120); gather band fits L2.
__device__ __forceinline__ int xcd_chunk_swizzle(int bid, int nwg) {
    const int NX = 8;
    int q = nwg / NX, r = nwg % NX;
    int xcd = bid % NX;
    int lid = bid / NX;
    return (xcd < r) ? (xcd * (q + 1) + lid)
                     : (r * (q + 1) + (xcd - r) * q + lid);
}

// ---------- pass 1: interleave src [N,3,HS,WS] fp32 -> [N,HS,WS] {bf16 c0,c1,c2,pad} (8B/px) ----------
__global__ __launch_bounds__(256) void interleave_kernel(
    const float* __restrict__ src, uint4* __restrict__ ws)
{
    const size_t HWs = (size_t)HS_ * WS_;
    size_t g = (size_t)blockIdx.x * blockDim.x + threadIdx.x;  // group of 4 pixels
    size_t base = g * 4;
    if (base >= (size_t)N_ * HWs) return;
    int n = (int)(base / HWs);
    size_t p = base - (size_t)n * HWs;
    const float* s = src + (size_t)n * C_ * HWs + p;
    // src fp32 is read exactly once -> nontemporal, don't evict useful lines.
    fx4 c0 = __builtin_nontemporal_load((const fx4*)(s));
    fx4 c1 = __builtin_nontemporal_load((const fx4*)(s + HWs));
    fx4 c2 = __builtin_nontemporal_load((const fx4*)(s + 2 * HWs));

    uint4 A, B;
    A.x = (unsigned)f2bf(c0.x) | ((unsigned)f2bf(c1.x) << 16);
    A.y = (unsigned)f2bf(c2.x);
    A.z = (unsigned)f2bf(c0.y) | ((unsigned)f2bf(c1.y) << 16);
    A.w = (unsigned)f2bf(c2.y);
    B.x = (unsigned)f2bf(c0.z) | ((unsigned)f2bf(c1.z) << 16);
    B.y = (unsigned)f2bf(c2.z);
    B.z = (unsigned)f2bf(c0.w) | ((unsigned)f2bf(c1.w) << 16);
    B.w = (unsigned)f2bf(c2.w);

    size_t o = base / 2;  // uint4 = 2 pixels
    // ws is read back by pass 2 -> KEEP cached (L3 should retain it).
    ws[o]     = A;
    ws[o + 1] = B;
}

// ---------- pass 2: warp + bilinear gather, 16B pixel-pair loads ----------
__global__ __launch_bounds__(256) void warp_main_kernel(
    const float* __restrict__ depth,   // [N,1,HD,WD]
    const uint2* __restrict__ wsrc,    // [N,HS,WS] packed
    const float* __restrict__ abc,     // [3,HD,WD]
    const float* __restrict__ tr,      // [3]
    const float* __restrict__ pin,     // [4]
    float* __restrict__ out)           // [N,C,HD,WD]
{
    const int HW = HD_ * WD_;
    int swz = xcd_chunk_swizzle(blockIdx.x, gridDim.x);
    int idx = swz * blockDim.x + threadIdx.x;
    if (idx >= N_ * HW) return;

    int n  = idx / HW;
    int hw = idx - n * HW;

    // depth read exactly once -> nontemporal.
    float d = __builtin_nontemporal_load(&depth[idx]);
    // abc shared by all XCDs marching in row-lockstep -> keep cached.
    float a = abc[hw];
    float b = abc[HW + hw];
    float c = abc[2 * HW + hw];

    float tx = tr[0], ty = tr[1], tz = tr[2];
    float fu = pin[0], fv = pin[1], du = pin[2], dv = pin[3];

    float denom = c * d + tz;
    float inv = 1.0f / denom;
    float xx = (a * d + tx) * inv;
    float yy = (b * d + ty) * inv;
    float uu = fu * xx + du;
    float vv = fv * yy + dv;

    float gx = 2.0f * uu / (float)(WS_ - 1) - 1.0f;
    float gy = 2.0f * vv / (float)(HS_ - 1) - 1.0f;
    float x = ((gx + 1.0f) * (float)WS_ - 1.0f) * 0.5f;
    float y = ((gy + 1.0f) * (float)HS_ - 1.0f) * 0.5f;

    x = fminf(fmaxf(x, 0.0f), (float)(WS_ - 1));
    y = fminf(fmaxf(y, 0.0f), (float)(HS_ - 1));

    // Re-based clamp: x0 <= WS-2 so the pair {x0, x0+1} is always in-row.
    // Border (x == WS-1): x0 = WS-2, wx = 1.0 -> value-identical to the
    // torch border semantics (weight of px[WS-2] is exactly 0).
    int x0 = min((int)floorf(x), WS_ - 2);
    int y0 = min((int)floorf(y), HS_ - 2);
    float wx = x - (float)x0;
    float wy = y - (float)y0;

    float w00 = (1.0f - wy) * (1.0f - wx);
    float w01 = (1.0f - wy) * wx;
    float w10 = wy * (1.0f - wx);
    float w11 = wy * wx;

    const size_t HWs = (size_t)HS_ * WS_;
    const uint2* sn = wsrc + (size_t)n * HWs;
    // One 16B load per row covers both x-taps: {c0c1, c2, c0c1, c2}.
    u32x4 r0 = *(const u32x4a8*)(sn + (size_t)y0 * WS_ + x0);
    u32x4 r1 = *(const u32x4a8*)(sn + (size_t)(y0 + 1) * WS_ + x0);

    float* on = out + (size_t)n * C_ * HW + hw;

    // channel 0: low half of word0/word2
    float v0 = bf2f(r0.x & 0xFFFFu) * w00 + bf2f(r0.z & 0xFFFFu) * w01
             + bf2f(r1.x & 0xFFFFu) * w10 + bf2f(r1.z & 0xFFFFu) * w11;
    // channel 1: high half of word0/word2
    float v1 = bf2f(r0.x >> 16) * w00 + bf2f(r0.z >> 16) * w01
             + bf2f(r1.x >> 16) * w10 + bf2f(r1.z >> 16) * w11;
    // channel 2: low half of word1/word3
    float v2 = bf2f(r0.y & 0xFFFFu) * w00 + bf2f(r0.w & 0xFFFFu) * w01
             + bf2f(r1.y & 0xFFFFu) * w10 + bf2f(r1.w & 0xFFFFu) * w11;

    // out written once, never read -> nontemporal (don't churn L3).
    __builtin_nontemporal_store(v0, on);
    __builtin_nontemporal_store(v1, on + (size_t)HW);
    __builtin_nontemporal_store(v2, on + (size_t)2 * HW);
}

// ---------- fallback: round-1 planar kernel (used only if ws too small) ----------
__global__ __launch_bounds__(256) void warp_planar_kernel(
    const float* __restrict__ depth, const float* __restrict__ src,
    const float* __restrict__ abc, const float* __restrict__ tr,
    const float* __restrict__ pin, float* __restrict__ out)
{
    const int HW = HD_ * WD_;
    int idx = blockIdx.x * blockDim.x + threadIdx.x;
    if (idx >= N_ * HW) return;
    int n  = idx / HW;
    int hw = idx - n * HW;
    float d = depth[idx];
    float a = abc[hw];
    float b = abc[HW + hw];
    float c = abc[2 * HW + hw];
    float denom = c * d + tr[2];
    float inv = 1.0f / denom;
    float uu = pin[0] * ((a * d + tr[0]) * inv) + pin[2];
    float vv = pin[1] * ((b * d + tr[1]) * inv) + pin[3];
    float gx = 2.0f * uu / (float)(WS_ - 1) - 1.0f;
    float gy = 2.0f * vv / (float)(HS_ - 1) - 1.0f;
    float x = ((gx + 1.0f) * (float)WS_ - 1.0f) * 0.5f;
    float y = ((gy + 1.0f) * (float)HS_ - 1.0f) * 0.5f;
    x = fminf(fmaxf(x, 0.0f), (float)(WS_ - 1));
    y = fminf(fmaxf(y, 0.0f), (float)(HS_ - 1));
    float x0f = floorf(x), y0f = floorf(y);
    float wx = x - x0f, wy = y - y0f;
    int x0 = (int)x0f, y0 = (int)y0f;
    int x1 = min(x0 + 1, WS_ - 1);
    int y1 = min(y0 + 1, HS_ - 1);
    float w00 = (1.0f - wy) * (1.0f - wx), w01 = (1.0f - wy) * wx;
    float w10 = wy * (1.0f - wx), w11 = wy * wx;
    const size_t HWs = (size_t)HS_ * WS_;
    const float* sn = src + (size_t)n * C_ * HWs;
    int o00 = y0 * WS_ + x0, o01 = y0 * WS_ + x1;
    int o10 = y1 * WS_ + x0, o11 = y1 * WS_ + x1;
    float* on = out + (size_t)n * C_ * HW + hw;
#pragma unroll
    for (int ch = 0; ch < C_; ++ch) {
        const float* sc = sn + (size_t)ch * HWs;
        on[(size_t)ch * HW] = sc[o00] * w00 + sc[o01] * w01
                            + sc[o10] * w10 + sc[o11] * w11;
    }
}

extern "C" void kernel_launch(void* const* d_in, const int* in_sizes, int n_in,
                              void* d_out, int out_size, void* d_ws, size_t ws_size,
                              hipStream_t stream) {
    const float* depth = (const float*)d_in[0];
    const float* src   = (const float*)d_in[1];
    const float* abc   = (const float*)d_in[2];
    const float* tr    = (const float*)d_in[3];
    const float* pin   = (const float*)d_in[4];
    float* out = (float*)d_out;

    const size_t need = (size_t)N_ * HS_ * WS_ * 8;  // 8B per src pixel
    const int total = N_ * HD_ * WD_;
    const int block = 256;

    if (ws_size >= need) {
        const size_t src_px = (size_t)N_ * HS_ * WS_;
        const int g1 = (int)((src_px / 4 + block - 1) / block);
        interleave_kernel<<<g1, block, 0, stream>>>(src, (uint4*)d_ws);
        const int g2 = (total + block - 1) / block;
        warp_main_kernel<<<g2, block, 0, stream>>>(depth, (const uint2*)d_ws,
                                                   abc, tr, pin, out);
    } else {
        const int g = (total + block - 1) / block;
        warp_planar_kernel<<<g, block, 0, stream>>>(depth, src, abc, tr, pin, out);
    }
}